// Round 6
// baseline (11812.069 us; speedup 1.0000x reference)
//
#include <hip/hip_runtime.h>

// TrajLSTM: 2-layer LSTM (H=1024), T=64 steps + 16 autoregressive. B=1024, I=64.
//
// Round 6: barrier-free streaming GEMM. No LDS in the K-loop.
//  - h-state stored in MFMA A-fragment-major layout in global memory:
//    chunk(bb, kc) = 1 KB; lane l holds A[b = bb*32 + (l&31)][k = kc*16 + (l>>5)*8 .. +8].
//    GEMM epilogue transposes C-layout -> frag layout through per-wave LDS
//    scratch (intra-wave, no __syncthreads anywhere).
//  - Weights packed as B-fragment chunks: lane l -> W[n0 + (l&31)][kc*16 + (l>>5)*8..],
//    layout [u][kc][gate][1KB] so a wave's stream is contiguous; XCD-pinned by u.
//  - Wave tile 64 batch x 128 n (4 gates x 32 H): acc = 4x2x16 = 128 VGPR,
//    n_wave=128 kills the LDS bottleneck; m_wave=64 halves B re-reads.
//  - MFMA v_mfma_f32_32x32x16_f16; C/D: col=lane&31, row=(reg&3)+8*(reg>>2)+4*(lane>>5).
//  - One fused dispatch per main step {L2(t), L1(t+1), proj(t-1), xcopy(t+2)};
//    future phase serial. Work unit = 1 wave; blocks = 4 independent waves.

#define B_   1024
#define T_   64
#define I_   64
#define H_   1024
#define FUT_ 16
#define NST_ (T_ + FUT_)
#define OUTS (NST_ * I_)     // 5120, d_out row stride

typedef _Float16 half8_t  __attribute__((ext_vector_type(8)));
typedef float    f32x16   __attribute__((ext_vector_type(16)));

__device__ __forceinline__ float sigmoid_f(float x) {
    x = fminf(fmaxf(x, -30.f), 30.f);
    return __fdividef(1.f, 1.f + __expf(-x));
}
__device__ __forceinline__ float tanh_f(float x) {
    x = fminf(fmaxf(x, -15.f), 15.f);
    float e = __expf(2.f * x);
    return 1.f - 2.f * __fdividef(1.f, e + 1.f);
}

// ---------------- one-time packing ----------------------------------------
// W2F: [u 32][kc 128][g 4][1KB]   (L2: K = h1'(1024) | h2(1024))
// W1F: [u 32][kc 68][g 4][1KB]    (L1: K = h1(1024) | x(64); Whh1 then Wih1)
// WPF: [nt 2][kc 64][1KB]         (proj, 64 x 1024)
// SX0/SX1: x(0), x(1) in frag-major [bb 32][kc 4][1KB]
__global__ void convert_all(const float* __restrict__ x,
    const float* __restrict__ Wih1, const float* __restrict__ Whh1,
    const float* __restrict__ bih1, const float* __restrict__ bhh1,
    const float* __restrict__ Wih2, const float* __restrict__ Whh2,
    const float* __restrict__ bih2, const float* __restrict__ bhh2,
    const float* __restrict__ Wlin,
    _Float16* __restrict__ W2F, _Float16* __restrict__ W1F,
    _Float16* __restrict__ WPF,
    _Float16* __restrict__ SX0, _Float16* __restrict__ SX1,
    float* __restrict__ b1, float* __restrict__ b2)
{
    size_t idx = (size_t)blockIdx.x * 256 + threadIdx.x;
    const size_t G2 = 16384ull * 64;   // 32*128*4 chunks
    const size_t G1 = 8704ull * 64;    // 32*68*4
    const size_t GP = 128ull * 64;     // 2*64
    const size_t GX = 256ull * 64;     // 2*32*4
    if (idx < G2) {
        int c = (int)(idx >> 6), l = (int)(idx & 63);
        int g = c & 3, kc = (c >> 2) & 127, u = c >> 9;
        int row = (g << 10) + u * 32 + (l & 31);
        int k = kc * 16 + (l >> 5) * 8;
        const float* s = (k < 1024) ? &Wih2[(size_t)row * 1024 + k]
                                    : &Whh2[(size_t)row * 1024 + (k - 1024)];
        _Float16* o = W2F + (size_t)c * 512 + l * 8;
        #pragma unroll
        for (int i = 0; i < 8; ++i) o[i] = (_Float16)s[i];
    } else if ((idx -= G2) < G1) {
        int c = (int)(idx >> 6), l = (int)(idx & 63);
        int g = c & 3, rem = c >> 2;
        int kc = rem % 68, u = rem / 68;
        int row = (g << 10) + u * 32 + (l & 31);
        int k = kc * 16 + (l >> 5) * 8;
        const float* s = (k < 1024) ? &Whh1[(size_t)row * 1024 + k]
                                    : &Wih1[(size_t)row * 64 + (k - 1024)];
        _Float16* o = W1F + (size_t)c * 512 + l * 8;
        #pragma unroll
        for (int i = 0; i < 8; ++i) o[i] = (_Float16)s[i];
    } else if ((idx -= G1) < GP) {
        int c = (int)(idx >> 6), l = (int)(idx & 63);
        int kc = c & 63, nt = c >> 6;
        int n = nt * 32 + (l & 31);
        int k = kc * 16 + (l >> 5) * 8;
        const float* s = &Wlin[(size_t)n * 1024 + k];
        _Float16* o = WPF + (size_t)c * 512 + l * 8;
        #pragma unroll
        for (int i = 0; i < 8; ++i) o[i] = (_Float16)s[i];
    } else if ((idx -= GP) < GX) {
        int c = (int)(idx >> 6), l = (int)(idx & 63);
        int buf = c >> 7, bb = (c >> 2) & 31, kc = c & 3;
        int b = bb * 32 + (l & 31);
        int col = kc * 16 + (l >> 5) * 8;
        const float* s = &x[(size_t)b * (T_ * I_) + buf * 64 + col];
        _Float16* o = (buf ? SX1 : SX0) + ((size_t)(bb * 4 + kc)) * 512 + l * 8;
        #pragma unroll
        for (int i = 0; i < 8; ++i) o[i] = (_Float16)s[i];
    } else if ((idx -= GX) < 4096) {
        b1[idx] = bih1[idx] + bhh1[idx];
    } else if ((idx -= 4096) < 4096) {
        b2[idx] = bih2[idx] + bhh2[idx];
    }
}

// ---------------- GEMM + fused LSTM cell (one wave = 64 b x 128 n) --------
// A streams: seg0 = A0 (kcs0=64 chunks/bb, stride 64*512), seg1 = A1.
// Weight stream: WF0 + u*Kc*2048, 4 KB per kc. c-state is j-major: c[j*1024+b].
__device__ __forceinline__ void gemm_wave(
    const _Float16* __restrict__ A0, const _Float16* __restrict__ A1,
    const _Float16* __restrict__ WF0, const int Kc, const int strA1,
    const float* __restrict__ bias, float* __restrict__ cvec,
    _Float16* __restrict__ Hdst, _Float16* __restrict__ wl,
    const int unit, const int lane)
{
    const int u = unit & 31, mt = unit >> 5;
    const int m0 = mt * 64, bb0 = mt * 2;
    const int kcs0 = 64;

    const _Float16* wf  = WF0 + (size_t)u * Kc * 2048 + lane * 8;
    const _Float16* a00 = A0 + (size_t)bb0 * (64 * 512) + lane * 8;
    const _Float16* a01 = a00 + 64 * 512;
    const _Float16* a10 = A1 + (size_t)bb0 * strA1 + lane * 8;
    const _Float16* a11 = a10 + strA1;

    f32x16 acc[4][2];
    #pragma unroll
    for (int g = 0; g < 4; ++g)
        #pragma unroll
        for (int rt = 0; rt < 2; ++rt)
            #pragma unroll
            for (int e = 0; e < 16; ++e) acc[g][rt][e] = 0.f;

    half8_t afc[2], bfc[4], afn[2], bfn[4];
    afc[0] = *(const half8_t*)a00;
    afc[1] = *(const half8_t*)a01;
    #pragma unroll
    for (int g = 0; g < 4; ++g) bfc[g] = *(const half8_t*)(wf + g * 512);

    #pragma unroll 2
    for (int kc = 0; kc < Kc; ++kc) {
        const int kn = kc + 1;
        if (kn < Kc) {
            if (kn < kcs0) {
                afn[0] = *(const half8_t*)(a00 + (size_t)kn * 512);
                afn[1] = *(const half8_t*)(a01 + (size_t)kn * 512);
            } else {
                const int k2 = kn - kcs0;
                afn[0] = *(const half8_t*)(a10 + (size_t)k2 * 512);
                afn[1] = *(const half8_t*)(a11 + (size_t)k2 * 512);
            }
            const _Float16* wp = wf + (size_t)kn * 2048;
            #pragma unroll
            for (int g = 0; g < 4; ++g) bfn[g] = *(const half8_t*)(wp + g * 512);
        }
        #pragma unroll
        for (int g = 0; g < 4; ++g) {
            acc[g][0] = __builtin_amdgcn_mfma_f32_32x32x16_f16(afc[0], bfc[g], acc[g][0], 0, 0, 0);
            acc[g][1] = __builtin_amdgcn_mfma_f32_32x32x16_f16(afc[1], bfc[g], acc[g][1], 0, 0, 0);
        }
        afc[0] = afn[0]; afc[1] = afn[1];
        #pragma unroll
        for (int g = 0; g < 4; ++g) bfc[g] = bfn[g];
    }

    // ---- cell epilogue (lane holds i,f,g,o of same (b,j)) ----
    const int j = u * 32 + (lane & 31);
    const float bi = bias[j], bff = bias[1024 + j];
    const float bg = bias[2048 + j], bo = bias[3072 + j];
    const int hi4 = (lane >> 5) * 4;
    float* cb = cvec + (size_t)j * 1024 + m0;
    #pragma unroll
    for (int rt = 0; rt < 2; ++rt) {
        #pragma unroll
        for (int q = 0; q < 4; ++q) {
            const int rbase = rt * 32 + q * 8 + hi4;
            float4 c4 = *(float4*)(cb + rbase);
            #pragma unroll
            for (int e = 0; e < 4; ++e) {
                const int reg = q * 4 + e;
                float gi = sigmoid_f(acc[0][rt][reg] + bi);
                float gf = sigmoid_f(acc[1][rt][reg] + bff);
                float gv = tanh_f(acc[2][rt][reg] + bg);
                float go = sigmoid_f(acc[3][rt][reg] + bo);
                float cn = gf * (&c4.x)[e] + gi * gv;
                (&c4.x)[e] = cn;
                wl[(rbase + e) * 40 + (lane & 31)] = (_Float16)(go * tanh_f(cn));
            }
            *(float4*)(cb + rbase) = c4;
        }
    }
    // ---- transpose to A-fragment chunks (intra-wave, waitcnt-ordered) ----
    #pragma unroll
    for (int rt = 0; rt < 2; ++rt)
        #pragma unroll
        for (int cj = 0; cj < 2; ++cj) {
            half8_t v = *(const half8_t*)&wl[(rt * 32 + (lane & 31)) * 40
                                             + cj * 16 + (lane >> 5) * 8];
            *(half8_t*)(Hdst + (((size_t)(bb0 + rt) * 64) + (u * 2 + cj)) * 512
                        + lane * 8) = v;
        }
}

// ---------------- out projection (one wave = 64 b x 64 i) ------------------
__device__ __forceinline__ void proj_wave(
    const _Float16* __restrict__ A0, const _Float16* __restrict__ WF,
    const float* __restrict__ blin, float* __restrict__ outp,
    _Float16* __restrict__ xdst, _Float16* __restrict__ wl,
    const int unit, const int lane)
{
    const int mt = unit;
    const int m0 = mt * 64, bb0 = mt * 2;
    const _Float16* wf  = WF + lane * 8;
    const _Float16* a00 = A0 + (size_t)bb0 * (64 * 512) + lane * 8;
    const _Float16* a01 = a00 + 64 * 512;

    f32x16 acc[2][2];   // [nt][rt]
    #pragma unroll
    for (int n = 0; n < 2; ++n)
        #pragma unroll
        for (int rt = 0; rt < 2; ++rt)
            #pragma unroll
            for (int e = 0; e < 16; ++e) acc[n][rt][e] = 0.f;

    half8_t afc[2], bfc[2], afn[2], bfn[2];
    afc[0] = *(const half8_t*)a00;
    afc[1] = *(const half8_t*)a01;
    bfc[0] = *(const half8_t*)(wf);
    bfc[1] = *(const half8_t*)(wf + 64 * 512);

    #pragma unroll 2
    for (int kc = 0; kc < 64; ++kc) {
        const int kn = kc + 1;
        if (kn < 64) {
            afn[0] = *(const half8_t*)(a00 + (size_t)kn * 512);
            afn[1] = *(const half8_t*)(a01 + (size_t)kn * 512);
            bfn[0] = *(const half8_t*)(wf + (size_t)kn * 512);
            bfn[1] = *(const half8_t*)(wf + (size_t)(64 + kn) * 512);
        }
        #pragma unroll
        for (int n = 0; n < 2; ++n) {
            acc[n][0] = __builtin_amdgcn_mfma_f32_32x32x16_f16(afc[0], bfc[n], acc[n][0], 0, 0, 0);
            acc[n][1] = __builtin_amdgcn_mfma_f32_32x32x16_f16(afc[1], bfc[n], acc[n][1], 0, 0, 0);
        }
        afc[0] = afn[0]; afc[1] = afn[1]; bfc[0] = bfn[0]; bfc[1] = bfn[1];
    }

    const int hi4 = (lane >> 5) * 4;
    #pragma unroll
    for (int n = 0; n < 2; ++n) {
        const int i = n * 32 + (lane & 31);
        const float bl = blin[i];
        #pragma unroll
        for (int rt = 0; rt < 2; ++rt)
            #pragma unroll
            for (int q = 0; q < 4; ++q)
                #pragma unroll
                for (int e = 0; e < 4; ++e) {
                    const int rloc = rt * 32 + q * 8 + hi4 + e;
                    float s = acc[n][rt][q * 4 + e] + bl;
                    outp[(size_t)(m0 + rloc) * OUTS + i] = s;
                    if (xdst) wl[rloc * 72 + i] = (_Float16)s;
                }
    }
    if (xdst) {
        #pragma unroll
        for (int rt = 0; rt < 2; ++rt)
            #pragma unroll
            for (int kc = 0; kc < 4; ++kc) {
                half8_t v = *(const half8_t*)&wl[(rt * 32 + (lane & 31)) * 72
                                                 + kc * 16 + (lane >> 5) * 8];
                *(half8_t*)(xdst + ((size_t)(bb0 + rt) * 4 + kc) * 512 + lane * 8) = v;
            }
    }
}

// ---------------- x input copy to frag-major -------------------------------
__device__ __forceinline__ void copy_wave(const float* __restrict__ xsrc,
    _Float16* __restrict__ xdst, const int unit, const int lane)
{
    #pragma unroll
    for (int c = 0; c < 16; ++c) {
        int chunk = unit * 16 + c;
        int bb = chunk >> 2, kc = chunk & 3;
        int b = bb * 32 + (lane & 31);
        int col = kc * 16 + (lane >> 5) * 8;
        const float* s = xsrc + (size_t)b * (T_ * I_) + col;
        half8_t v;
        #pragma unroll
        for (int i = 0; i < 8; ++i) v[i] = (_Float16)s[i];
        *(half8_t*)(xdst + (size_t)chunk * 512 + lane * 8) = v;
    }
}

// ---------------- fused multi-role dispatch --------------------------------
struct StepArgs {
    int nL2, nL1, nProj, nCopy;
    const _Float16 *a2h1, *a2h2; _Float16* h2d;
    const _Float16 *a1h1, *a1x;  _Float16* h1d;
    const _Float16* pA; float* pOut; _Float16* pX;
    const float* xsrc; _Float16* xcd;
    const _Float16 *W2F, *W1F, *WPF;
    const float *b1, *b2, *blin;
    float *c1, *c2;
};

__global__ __launch_bounds__(256, 2) void fused_step(StepArgs a) {
    __shared__ _Float16 lds[4][4608];
    const int wid = threadIdx.x >> 6, lane = threadIdx.x & 63;
    _Float16* wl = lds[wid];
    int unit = blockIdx.x * 4 + wid;
    if (unit < a.nL2) {
        gemm_wave(a.a2h1, a.a2h2, a.W2F, 128, 64 * 512,
                  a.b2, a.c2, a.h2d, wl, unit, lane);
    } else if ((unit -= a.nL2) < a.nL1) {
        gemm_wave(a.a1h1, a.a1x, a.W1F, 68, 4 * 512,
                  a.b1, a.c1, a.h1d, wl, unit, lane);
    } else if ((unit -= a.nL1) < a.nProj) {
        proj_wave(a.pA, a.WPF, a.blin, a.pOut, a.pX, wl, unit, lane);
    } else if ((unit -= a.nProj) < a.nCopy) {
        copy_wave(a.xsrc, a.xcd, unit, lane);
    }
}

// ---------------------------------------------------------------------------
extern "C" void kernel_launch(void* const* d_in, const int* in_sizes, int n_in,
                              void* d_out, int out_size, void* d_ws, size_t ws_size,
                              hipStream_t stream) {
    (void)in_sizes; (void)n_in; (void)out_size; (void)ws_size;
    const float* x    = (const float*)d_in[0];
    const float* Wih1 = (const float*)d_in[1];
    const float* Whh1 = (const float*)d_in[2];
    const float* bih1 = (const float*)d_in[3];
    const float* bhh1 = (const float*)d_in[4];
    const float* Wih2 = (const float*)d_in[5];
    const float* Whh2 = (const float*)d_in[6];
    const float* bih2 = (const float*)d_in[7];
    const float* bhh2 = (const float*)d_in[8];
    const float* Wlin = (const float*)d_in[9];
    const float* blin = (const float*)d_in[10];
    float* out = (float*)d_out;

    char* p = (char*)d_ws;
    auto alloc = [&](size_t bytes) {
        char* r = p; p += (bytes + 255) & ~(size_t)255; return r;
    };
    _Float16* W2F = (_Float16*)alloc(16384ull * 1024);
    _Float16* W1F = (_Float16*)alloc(8704ull * 1024);
    _Float16* WPF = (_Float16*)alloc(128ull * 1024);
    _Float16* SH1[3], * SH2[3], * SX[3];
    for (int i = 0; i < 3; ++i) SH1[i] = (_Float16*)alloc(2048ull * 1024);
    for (int i = 0; i < 3; ++i) SH2[i] = (_Float16*)alloc(2048ull * 1024);
    for (int i = 0; i < 3; ++i) SX[i]  = (_Float16*)alloc(128ull * 1024);
    float* c1 = (float*)alloc((size_t)B_ * H_ * 4);
    float* c2 = (float*)alloc((size_t)B_ * H_ * 4);
    float* b1 = (float*)alloc(4096 * 4);
    float* b2 = (float*)alloc(4096 * 4);

    hipMemsetAsync(SH1[0], 0, 2048ull * 1024, stream);
    hipMemsetAsync(SH2[0], 0, 2048ull * 1024, stream);
    hipMemsetAsync(c1, 0, (size_t)B_ * H_ * 4, stream);
    hipMemsetAsync(c2, 0, (size_t)B_ * H_ * 4, stream);

    convert_all<<<6400, 256, 0, stream>>>(x, Wih1, Whh1, bih1, bhh1,
        Wih2, Whh2, bih2, bhh2, Wlin, W2F, W1F, WPF, SX[0], SX[1], b1, b2);

    StepArgs a{};
    a.W2F = W2F; a.W1F = W1F; a.WPF = WPF;
    a.b1 = b1; a.b2 = b2; a.blin = blin;
    a.c1 = c1; a.c2 = c2;

    // prologue: L1(0): h1(0) <- [h1(-1)=0 | x(0)]
    {
        StepArgs q = a;
        q.nL2 = 0; q.nL1 = 512; q.nProj = 0; q.nCopy = 0;
        q.a1h1 = SH1[0]; q.a1x = SX[0]; q.h1d = SH1[1];
        fused_step<<<128, 256, 0, stream>>>(q);
    }
    // main: D_t = {L2(t), L1(t+1), proj(t-1), xcopy(t+2)}
    for (int t = 0; t <= 62; ++t) {
        const int pp = t % 3, qq = (t + 1) % 3, rr = (t + 2) % 3;
        StepArgs q = a;
        q.nL2 = 512; q.nL1 = 512;
        q.nProj = (t >= 1) ? 16 : 0;
        q.nCopy = (t <= 61) ? 8 : 0;
        q.a2h1 = SH1[qq]; q.a2h2 = SH2[pp]; q.h2d = SH2[qq];
        q.a1h1 = SH1[qq]; q.a1x = SX[qq];   q.h1d = SH1[rr];
        q.pA = SH2[pp]; q.pOut = out + (size_t)(t - 1) * I_; q.pX = nullptr;
        q.xsrc = x + (size_t)(t + 2) * I_; q.xcd = SX[rr];
        const int grid = (q.nL2 + q.nL1 + q.nProj + q.nCopy) / 4;
        fused_step<<<grid, 256, 0, stream>>>(q);
    }
    // t=63: {L2(63), proj(62)}
    {
        StepArgs q = a;
        q.nL2 = 512; q.nL1 = 0; q.nProj = 16; q.nCopy = 0;
        q.a2h1 = SH1[1]; q.a2h2 = SH2[0]; q.h2d = SH2[1];
        q.pA = SH2[0]; q.pOut = out + (size_t)62 * I_; q.pX = nullptr;
        fused_step<<<132, 256, 0, stream>>>(q);
    }
    // proj(63) + x(64) feedback
    {
        StepArgs q = a;
        q.nL2 = 0; q.nL1 = 0; q.nProj = 16; q.nCopy = 0;
        q.pA = SH2[1]; q.pOut = out + (size_t)63 * I_; q.pX = SX[1];
        fused_step<<<4, 256, 0, stream>>>(q);
    }
    // future: serial L1(t) -> L2(t) -> proj(t)+feedback
    for (int t = T_; t < NST_; ++t) {
        const int s = t % 3, s1 = (t + 1) % 3;
        {
            StepArgs q = a;
            q.nL2 = 0; q.nL1 = 512; q.nProj = 0; q.nCopy = 0;
            q.a1h1 = SH1[s]; q.a1x = SX[s]; q.h1d = SH1[s1];
            fused_step<<<128, 256, 0, stream>>>(q);
        }
        {
            StepArgs q = a;
            q.nL2 = 512; q.nL1 = 0; q.nProj = 0; q.nCopy = 0;
            q.a2h1 = SH1[s1]; q.a2h2 = SH2[s]; q.h2d = SH2[s1];
            fused_step<<<128, 256, 0, stream>>>(q);
        }
        {
            StepArgs q = a;
            q.nL2 = 0; q.nL1 = 0; q.nProj = 16; q.nCopy = 0;
            q.pA = SH2[s1]; q.pOut = out + (size_t)t * I_;
            q.pX = (t + 1 < NST_) ? SX[s1] : nullptr;
            fused_step<<<4, 256, 0, stream>>>(q);
        }
    }
}

// Round 7
// 3560.519 us; speedup vs baseline: 3.3175x; 3.3175x over previous
//
#include <hip/hip_runtime.h>

// TrajLSTM: 2-layer LSTM (H=1024), T=64 steps + 16 autoregressive. B=1024, I=64.
// fp16 MFMA GEMMs, fused LSTM-cell epilogue, fp16-MFMA out-proj.
//
// State rows (fp16, stride 2176): [h1(1024) | x(64) | pad(64) | h2(1024)],
// three buffers rotating by t%3; one fused main dispatch = {L2(t), L1(t+1),
// proj(t-1), xcopy(t+2)} (mutually independent).
//
// Round 7 (revert round-6 streaming; fix round-5's occupancy + future phase):
//  - gemm tile m64 x BK128, double-buffered LDS (2 x 16 KB), ONE barrier/iter;
//    grid 1072 blocks, __launch_bounds__(256,3) -> 3 blocks/CU resident.
//  - XOR-granule swizzle (0 bank conflicts, verified r4/r5), global_load_lds
//    staging, bf register prefetch, XCD weight pinning (all verified).
//  - Future phase: projection composed into layer 1 (x(t+1)=h2@Wlin^T+b is
//    linear): gates1 = h1@Whh1^T + h2@(Wih1*Wlin)^T + (b1 + Wih1*b_lin).
//    2 dispatches/step {L1'(t)+proj(t-1)},{L2(t)}; proj off critical path.

#define B_   1024
#define T_   64
#define I_   64
#define H_   1024
#define FUT_ 16
#define NST_ (T_ + FUT_)
#define SROW 2176

typedef _Float16 half8_t  __attribute__((ext_vector_type(8)));
typedef float    float4_t __attribute__((ext_vector_type(4)));

typedef __attribute__((address_space(1))) const unsigned int g_u32;
typedef __attribute__((address_space(3))) unsigned int l_u32;

__device__ __forceinline__ void load_lds16(const _Float16* g, _Float16* l) {
    __builtin_amdgcn_global_load_lds((g_u32*)g, (l_u32*)l, 16, 0, 0);
}

__device__ __forceinline__ float sigmoid_f(float x) {
    x = fminf(fmaxf(x, -30.f), 30.f);
    return __fdividef(1.f, 1.f + __expf(-x));
}
__device__ __forceinline__ float tanh_f(float x) {
    x = fminf(fmaxf(x, -15.f), 15.f);
    float e = __expf(2.f * x);
    return 1.f - 2.f * __fdividef(1.f, e + 1.f);
}

// ---------------- one-time conversion / packing ----------------------------
// W1p: [hgrp 64][kstep 36][gate 4][1KB]  (K=1152: Whh1 | Wih1 | pad0)
// W2p: [hgrp 64][kstep 64][gate 4][1KB]  (K=2048: Wih2 | Whh2)
// Wlp: [hgrp 4 ][kstep 32][1KB]          (64 x 1024)
__global__ void convert_all(const float* __restrict__ x,
    const float* __restrict__ Wih1, const float* __restrict__ Whh1,
    const float* __restrict__ bih1, const float* __restrict__ bhh1,
    const float* __restrict__ Wih2, const float* __restrict__ Whh2,
    const float* __restrict__ bih2, const float* __restrict__ bhh2,
    const float* __restrict__ Wlin,
    _Float16* __restrict__ W1p, _Float16* __restrict__ W2p,
    _Float16* __restrict__ Wlp,
    _Float16* __restrict__ S0x, _Float16* __restrict__ S1x,
    float* __restrict__ b1, float* __restrict__ b2)
{
    size_t idx = (size_t)blockIdx.x * 256 + threadIdx.x;
    const size_t nc1 = 589824;    // 4096*1152/8
    const size_t nc2 = 1048576;   // 4096*2048/8
    const size_t nc3 = 8192;      // 64*1024/8
    const size_t nx  = 65536;     // B_*I_
    if (idx < nc1) {
        int c = (int)idx;
        int lane = c & 63, g = (c >> 6) & 3, rem = c >> 8;
        int j = rem % 36, hgrp = rem / 36;
        int row = (g << 10) + hgrp * 16 + (lane & 15);
        int kb = j * 32 + (lane >> 4) * 8;
        _Float16* o = &W1p[(size_t)c * 8];
        if (kb < 1024) {
            #pragma unroll
            for (int i = 0; i < 8; ++i) o[i] = (_Float16)Whh1[(size_t)row * 1024 + kb + i];
        } else if (kb < 1088) {
            #pragma unroll
            for (int i = 0; i < 8; ++i) o[i] = (_Float16)Wih1[row * 64 + (kb - 1024) + i];
        } else {
            #pragma unroll
            for (int i = 0; i < 8; ++i) o[i] = (_Float16)0.f;
        }
    } else if ((idx -= nc1) < nc2) {
        int c = (int)idx;
        int lane = c & 63, g = (c >> 6) & 3, rem = c >> 8;
        int j = rem & 63, hgrp = rem >> 6;
        int row = (g << 10) + hgrp * 16 + (lane & 15);
        int kb = j * 32 + (lane >> 4) * 8;
        _Float16* o = &W2p[(size_t)c * 8];
        if (kb < 1024) {
            #pragma unroll
            for (int i = 0; i < 8; ++i) o[i] = (_Float16)Wih2[(size_t)row * 1024 + kb + i];
        } else {
            #pragma unroll
            for (int i = 0; i < 8; ++i) o[i] = (_Float16)Whh2[(size_t)row * 1024 + kb - 1024 + i];
        }
    } else if ((idx -= nc2) < nc3) {
        int c = (int)idx;
        int lane = c & 63, j = (c >> 6) & 31, hgrp = c >> 11;
        int row = hgrp * 16 + (lane & 15);
        int kb = j * 32 + (lane >> 4) * 8;
        _Float16* o = &Wlp[(size_t)c * 8];
        #pragma unroll
        for (int i = 0; i < 8; ++i) o[i] = (_Float16)Wlin[(size_t)row * 1024 + kb + i];
    } else if ((idx -= nc3) < nx) {
        int b = (int)(idx >> 6), i = (int)(idx & 63);
        S0x[(size_t)b * SROW + i] = (_Float16)x[(size_t)b * (T_ * I_) + i];
    } else if ((idx -= nx) < nx) {
        int b = (int)(idx >> 6), i = (int)(idx & 63);
        S1x[(size_t)b * SROW + i] = (_Float16)x[(size_t)b * (T_ * I_) + 64 + i];
    } else if ((idx -= nx) < 4096) {
        b1[idx] = bih1[idx] + bhh1[idx];
    } else if ((idx -= 4096) < 4096) {
        b2[idx] = bih2[idx] + bhh2[idx];
    }
}

// W1c2: [hgrp 64][kstep 64][gate 4][1KB]  (K=2048: Whh1 | Wih1@Wlin)
// bc1[n] = b1[n] + Wih1[n,:]@b_lin   (runs after convert_all: reads b1)
__global__ void compose_pack(const float* __restrict__ Wih1,
    const float* __restrict__ Whh1, const float* __restrict__ Wlin,
    const float* __restrict__ blin, const float* __restrict__ b1in,
    _Float16* __restrict__ W1c2, float* __restrict__ bc1)
{
    size_t idx = (size_t)blockIdx.x * 256 + threadIdx.x;
    const size_t NC = 1048576;   // 4096*2048/8
    if (idx < NC) {
        int c = (int)idx;
        int lane = c & 63, g = (c >> 6) & 3, rem = c >> 8;
        int j = rem & 63, hgrp = rem >> 6;
        int row = (g << 10) + hgrp * 16 + (lane & 15);
        int kb = j * 32 + (lane >> 4) * 8;
        _Float16* o = &W1c2[(size_t)c * 8];
        if (kb < 1024) {
            #pragma unroll
            for (int i = 0; i < 8; ++i) o[i] = (_Float16)Whh1[(size_t)row * 1024 + kb + i];
        } else {
            const int h = kb - 1024;
            float acc[8] = {0, 0, 0, 0, 0, 0, 0, 0};
            for (int i2 = 0; i2 < 64; ++i2) {
                float wv = Wih1[row * 64 + i2];
                const float* wl = &Wlin[(size_t)i2 * 1024 + h];
                #pragma unroll
                for (int e = 0; e < 8; ++e) acc[e] += wv * wl[e];
            }
            #pragma unroll
            for (int e = 0; e < 8; ++e) o[e] = (_Float16)acc[e];
        }
    } else if ((idx -= NC) < 4096) {
        int n = (int)idx;
        float s = b1in[n];
        for (int i2 = 0; i2 < 64; ++i2) s += Wih1[n * 64 + i2] * blin[i2];
        bc1[n] = s;
    }
}

// ---------------- GEMM + fused LSTM cell -----------------------------------
// Block tile: 64 batch x 32 H x 4 gates; 4 waves = 2 hw (H) x 2 kh (split-K).
// sAb: 2 x (64 rows x 128 halves) = 32 KB; granule swizzle p = g ^ (row&15).
__device__ __forceinline__ void gemm_body(_Float16* sAb,
    const _Float16* __restrict__ Alo, const _Float16* __restrict__ Ahi,
    const _Float16* __restrict__ Wp, const int iters, const int Ksh,
    const float* __restrict__ bias, float* __restrict__ cvec,
    _Float16* __restrict__ hdst, const int unit)
{
    const int tid = threadIdx.x;
    const int lane = tid & 63, w = tid >> 6;
    const int hw = w & 1, kh = w >> 1;
    const int lr = lane & 15, lq = lane >> 4;
    const int ht = ((unit & 7) << 2) | ((unit >> 3) & 3);   // XCD-pinned H tile
    const int mt = unit >> 5;                                // 0..15
    const int h0 = ht * 32, m0 = mt * 64;
    const int hgrp = ht * 2 + hw;

    const char* wptr = (const char*)Wp
        + ((size_t)hgrp * (2 * Ksh) + (size_t)kh * Ksh) * 4096
        + (size_t)lane * 16;

    // staging: round s (0..3): thread t -> row (t>>4)+s*16, phys granule t&15;
    // logical granule gg = (t&15) ^ (row&15) (s-invariant).
    const int srow0 = tid >> 4, pg = tid & 15;
    const int gg = pg ^ (srow0 & 15);
    const _Float16* asrc = (gg < 8 ? Alo : Ahi) + (gg & 7) * 8
                         + (size_t)(m0 + srow0) * SROW;

    // af read offset (halves): row*128 + ((kh*8 + ks*4 + lq) ^ (row&15))*8
    const int ag0 = ((kh * 8 + lq) ^ lr) * 8;
    const int ag1 = ((kh * 8 + 4 + lq) ^ lr) * 8;

    float4_t acc[4][4];
    #pragma unroll
    for (int g = 0; g < 4; ++g)
        #pragma unroll
        for (int rt = 0; rt < 4; ++rt)
            #pragma unroll
            for (int e = 0; e < 4; ++e) acc[g][rt][e] = 0.f;

    half8_t bfc[8], bfn[8];
    #pragma unroll
    for (int q = 0; q < 8; ++q)
        bfc[q] = *(const half8_t*)(wptr + q * 1024);

    // prologue DMA for iter 0 into buf0
    #pragma unroll
    for (int s = 0; s < 4; ++s)
        load_lds16(asrc + (size_t)s * 16 * SROW, sAb + tid * 8 + s * 2048);

    for (int i = 0; i < iters; ++i) {
        __syncthreads();   // vmcnt(0) drain: DMA(i) + bf(i) complete
        _Float16* cur = sAb + (i & 1) * 8192;
        if (i + 1 < iters) {
            _Float16* nxt = sAb + ((i + 1) & 1) * 8192;
            const _Float16* an = asrc + (size_t)(i + 1) * 64;
            #pragma unroll
            for (int s = 0; s < 4; ++s)
                load_lds16(an + (size_t)s * 16 * SROW, nxt + tid * 8 + s * 2048);
            const char* wn = wptr + 8192;
            #pragma unroll
            for (int q = 0; q < 8; ++q)
                bfn[q] = *(const half8_t*)(wn + q * 1024);
        }
        #pragma unroll
        for (int ks = 0; ks < 2; ++ks) {
            const int ag = ks ? ag1 : ag0;
            #pragma unroll
            for (int rt = 0; rt < 4; ++rt) {
                half8_t af = *(const half8_t*)&cur[(rt * 16 + lr) * 128 + ag];
                #pragma unroll
                for (int g = 0; g < 4; ++g)
                    acc[g][rt] = __builtin_amdgcn_mfma_f32_16x16x32_f16(
                        af, bfc[ks * 4 + g], acc[g][rt], 0, 0, 0);
            }
        }
        wptr += 8192;
        #pragma unroll
        for (int q = 0; q < 8; ++q) bfc[q] = bfn[q];
    }
    __syncthreads();

    // split-K combine through LDS (2 rounds x 2 gates, 16 KB scratch)
    float* scr = (float*)sAb;
    #pragma unroll
    for (int gp = 0; gp < 2; ++gp) {
        if (kh == 1) {
            #pragma unroll
            for (int g2 = 0; g2 < 2; ++g2)
                #pragma unroll
                for (int rt = 0; rt < 4; ++rt) {
                    int slot = ((hw * 2 + g2) * 4 + rt) * 64 + lane;
                    *(float4_t*)&scr[slot * 4] = acc[gp * 2 + g2][rt];
                }
        }
        __syncthreads();
        if (kh == 0) {
            #pragma unroll
            for (int g2 = 0; g2 < 2; ++g2)
                #pragma unroll
                for (int rt = 0; rt < 4; ++rt) {
                    int slot = ((hw * 2 + g2) * 4 + rt) * 64 + lane;
                    acc[gp * 2 + g2][rt] += *(const float4_t*)&scr[slot * 4];
                }
        }
        __syncthreads();
    }
    if (kh != 0) return;

    const int j = h0 + hw * 16 + lr;
    const float bi = bias[j], bff = bias[1024 + j];
    const float bg = bias[2048 + j], bo = bias[3072 + j];
    #pragma unroll
    for (int rt = 0; rt < 4; ++rt) {
        #pragma unroll
        for (int e = 0; e < 4; ++e) {
            const int brow = m0 + rt * 16 + lq * 4 + e;
            float gi = sigmoid_f(acc[0][rt][e] + bi);
            float gf = sigmoid_f(acc[1][rt][e] + bff);
            float gv = tanh_f(acc[2][rt][e] + bg);
            float go = sigmoid_f(acc[3][rt][e] + bo);
            const size_t ci = (size_t)brow * 1024 + j;
            float cn = gf * cvec[ci] + gi * gv;
            cvec[ci] = cn;
            hdst[(size_t)brow * SROW + j] = (_Float16)(go * tanh_f(cn));
        }
    }
}

// out-proj: 64 batch x 32 i tile, K=1024 fp16 MFMA (single 16 KB buffer).
__device__ __forceinline__ void proj_body(_Float16* sA,
    const _Float16* __restrict__ A, const _Float16* __restrict__ Wp,
    const float* __restrict__ blin, float* __restrict__ outp,
    const int unit)
{
    const int iters = 8;
    const int tid = threadIdx.x;
    const int lane = tid & 63, w = tid >> 6;
    const int hw = w & 1, kh = w >> 1;
    const int lr = lane & 15, lq = lane >> 4;
    const int ht = unit & 1, mt = unit >> 1;
    const int h0 = ht * 32, m0 = mt * 64;
    const int hgrp = ht * 2 + hw;

    const char* wptr = (const char*)Wp
        + ((size_t)hgrp * 32 + (size_t)kh * 16) * 1024 + (size_t)lane * 16;

    const int srow0 = tid >> 4, pg = tid & 15;
    const int gg = pg ^ (srow0 & 15);
    const _Float16* asrc = A + (size_t)(gg >> 3) * 512 + (gg & 7) * 8
                         + (size_t)(m0 + srow0) * SROW;
    _Float16* ldst = sA + tid * 8;
    const int ag0 = ((kh * 8 + lq) ^ lr) * 8;
    const int ag1 = ((kh * 8 + 4 + lq) ^ lr) * 8;

    float4_t acc[4];
    #pragma unroll
    for (int rt = 0; rt < 4; ++rt)
        #pragma unroll
        for (int e = 0; e < 4; ++e) acc[rt][e] = 0.f;

    half8_t b0 = *(const half8_t*)(wptr);
    half8_t b1v = *(const half8_t*)(wptr + 1024);
    for (int i = 0; i < iters; ++i) {
        #pragma unroll
        for (int s = 0; s < 4; ++s)
            load_lds16(asrc + (size_t)s * 16 * SROW + (size_t)i * 64,
                       ldst + s * 2048);
        __syncthreads();
        half8_t n0, n1;
        if (i + 1 < iters) {
            n0 = *(const half8_t*)(wptr + 2048);
            n1 = *(const half8_t*)(wptr + 3072);
        }
        half8_t af;
        #pragma unroll
        for (int rt = 0; rt < 4; ++rt) {
            af = *(const half8_t*)&sA[(rt * 16 + lr) * 128 + ag0];
            acc[rt] = __builtin_amdgcn_mfma_f32_16x16x32_f16(af, b0, acc[rt], 0, 0, 0);
        }
        #pragma unroll
        for (int rt = 0; rt < 4; ++rt) {
            af = *(const half8_t*)&sA[(rt * 16 + lr) * 128 + ag1];
            acc[rt] = __builtin_amdgcn_mfma_f32_16x16x32_f16(af, b1v, acc[rt], 0, 0, 0);
        }
        __syncthreads();
        wptr += 2048;
        b0 = n0; b1v = n1;
    }

    float* scr = (float*)sA;
    if (kh == 1) {
        #pragma unroll
        for (int rt = 0; rt < 4; ++rt) {
            int slot = (hw * 4 + rt) * 64 + lane;
            *(float4_t*)&scr[slot * 4] = acc[rt];
        }
    }
    __syncthreads();
    if (kh != 0) return;
    #pragma unroll
    for (int rt = 0; rt < 4; ++rt) {
        int slot = (hw * 4 + rt) * 64 + lane;
        acc[rt] += *(const float4_t*)&scr[slot * 4];
    }

    const int j = h0 + hw * 16 + lr;
    const float bj = blin[j];
    #pragma unroll
    for (int rt = 0; rt < 4; ++rt) {
        #pragma unroll
        for (int e = 0; e < 4; ++e) {
            const int brow = m0 + rt * 16 + lq * 4 + e;
            outp[(size_t)brow * (NST_ * I_) + j] = acc[rt][e] + bj;
        }
    }
}

// ---------------- fused multi-role dispatch --------------------------------
struct StepArgs {
    int nL2, nL1, nProj, nCopy;
    const _Float16 *l2Alo, *l2Ahi; _Float16* l2H; const float* l2b; float* c2;
    const _Float16 *l1Alo, *l1Ahi; _Float16* l1H; const float* l1b; float* c1;
    int l1Iters, l1Ksh; const _Float16* l1W;
    const _Float16* pA; float* pOut;
    const float* xsrc; _Float16* xdst;
    const _Float16 *W2p, *Wlp;
    const float* blin;
};

__global__ __launch_bounds__(256, 3) void fused_step(StepArgs a) {
    __shared__ __align__(16) _Float16 sA[16384];   // 32 KB
    int bid = blockIdx.x;
    if (bid < a.nL2) {
        gemm_body(sA, a.l2Alo, a.l2Ahi, a.W2p, 16, 32, a.l2b, a.c2, a.l2H, bid);
    } else if ((bid -= a.nL2) < a.nL1) {
        gemm_body(sA, a.l1Alo, a.l1Ahi, a.l1W, a.l1Iters, a.l1Ksh,
                  a.l1b, a.c1, a.l1H, bid);
    } else if ((bid -= a.nL1) < a.nProj) {
        proj_body(sA, a.pA, a.Wlp, a.blin, a.pOut, bid);
    } else {
        bid -= a.nProj;
        int base = bid * 256 + threadIdx.x;
        for (int k = base; k < B_ * I_; k += a.nCopy * 256) {
            int b = k >> 6, i = k & 63;
            a.xdst[(size_t)b * SROW + i] = (_Float16)a.xsrc[(size_t)b * (T_ * I_) + i];
        }
    }
}

// ---------------------------------------------------------------------------
extern "C" void kernel_launch(void* const* d_in, const int* in_sizes, int n_in,
                              void* d_out, int out_size, void* d_ws, size_t ws_size,
                              hipStream_t stream) {
    (void)in_sizes; (void)n_in; (void)out_size; (void)ws_size;
    const float* x    = (const float*)d_in[0];
    const float* Wih1 = (const float*)d_in[1];
    const float* Whh1 = (const float*)d_in[2];
    const float* bih1 = (const float*)d_in[3];
    const float* bhh1 = (const float*)d_in[4];
    const float* Wih2 = (const float*)d_in[5];
    const float* Whh2 = (const float*)d_in[6];
    const float* bih2 = (const float*)d_in[7];
    const float* bhh2 = (const float*)d_in[8];
    const float* Wlin = (const float*)d_in[9];
    const float* blin = (const float*)d_in[10];
    float* out = (float*)d_out;

    char* p = (char*)d_ws;
    auto alloc = [&](size_t bytes) {
        char* r = p; p += (bytes + 255) & ~(size_t)255; return r;
    };
    _Float16* W1p  = (_Float16*)alloc((size_t)4096 * 1152 * 2);
    _Float16* W2p  = (_Float16*)alloc((size_t)4096 * 2048 * 2);
    _Float16* W1c2 = (_Float16*)alloc((size_t)4096 * 2048 * 2);
    _Float16* Wlp  = (_Float16*)alloc((size_t)64 * 1024 * 2);
    _Float16* S[3];
    for (int i = 0; i < 3; ++i) S[i] = (_Float16*)alloc((size_t)B_ * SROW * 2);
    float* c1  = (float*)alloc((size_t)B_ * H_ * 4);
    float* c2  = (float*)alloc((size_t)B_ * H_ * 4);
    float* b1  = (float*)alloc(4096 * 4);
    float* b2  = (float*)alloc(4096 * 4);
    float* bc1 = (float*)alloc(4096 * 4);

    for (int i = 0; i < 3; ++i)
        hipMemsetAsync(S[i], 0, (size_t)B_ * SROW * 2, stream);
    hipMemsetAsync(c1, 0, (size_t)B_ * H_ * 4, stream);
    hipMemsetAsync(c2, 0, (size_t)B_ * H_ * 4, stream);

    {
        const size_t total = 589824 + 1048576 + 8192 + 65536 + 65536 + 8192;
        convert_all<<<(int)((total + 255) / 256), 256, 0, stream>>>(
            x, Wih1, Whh1, bih1, bhh1, Wih2, Whh2, bih2, bhh2, Wlin,
            W1p, W2p, Wlp, S[0] + 1024, S[1] + 1024, b1, b2);
        compose_pack<<<(int)((1048576 + 4096 + 255) / 256), 256, 0, stream>>>(
            Wih1, Whh1, Wlin, blin, b1, W1c2, bc1);
    }

    StepArgs a{};
    a.W2p = W2p; a.Wlp = Wlp; a.blin = blin;
    a.l2b = b2; a.c2 = c2; a.l1b = b1; a.c1 = c1;
    a.l1W = W1p; a.l1Iters = 9; a.l1Ksh = 18;

    // prologue: L1(0) alone (reads S[0] = [0|x(0)], writes h1(0) -> S[1])
    {
        StepArgs q = a;
        q.nL2 = 0; q.nL1 = 512; q.nProj = 0; q.nCopy = 0;
        q.l1Alo = S[0]; q.l1Ahi = S[0] + 576; q.l1H = S[1];
        fused_step<<<512, 256, 0, stream>>>(q);
    }

    // main phase: D_t = {L2(t), L1(t+1), proj(t-1), xcopy(t+2)}
    for (int t = 0; t <= 62; ++t) {
        _Float16* Sp = S[t % 3];
        _Float16* Sq = S[(t + 1) % 3];
        _Float16* Sn = S[(t + 2) % 3];
        StepArgs q = a;
        q.nL2 = 512; q.nL1 = 512;
        q.nProj = (t >= 1) ? 32 : 0;
        q.nCopy = (t <= 61) ? 16 : 0;
        q.l2Alo = Sq; q.l2Ahi = Sp + 1152; q.l2H = Sq + 1152;
        q.l1Alo = Sq; q.l1Ahi = Sq + 576; q.l1H = Sn;
        q.pA = Sp + 1152; q.pOut = out + (size_t)(t - 1) * I_;
        q.xsrc = x + (size_t)(t + 2) * I_; q.xdst = Sn + 1024;
        int grid = q.nL2 + q.nL1 + q.nProj + q.nCopy;
        fused_step<<<grid, 256, 0, stream>>>(q);
    }

    // t=63: {L2(63), proj(62)}  (h1(63) already in S[1], h2(63) -> S[1]+1152)
    {
        StepArgs q = a;
        q.nL2 = 512; q.nL1 = 0; q.nProj = 32; q.nCopy = 0;
        q.l2Alo = S[1]; q.l2Ahi = S[0] + 1152; q.l2H = S[1] + 1152;
        q.pA = S[0] + 1152; q.pOut = out + (size_t)62 * I_;
        fused_step<<<544, 256, 0, stream>>>(q);
    }

    // future phase: composed L1' (no x feedback needed).
    // step t: D1 = {L1'(t): [h1(t-1)|h2(t-1)] @ W1c2 -> h1(t), proj(t-1)};
    //         D2 = {L2(t): [h1(t)|h2(t-1)] -> h2(t)}.
    // Ping-pong S[1] <-> S[2]: read Sp, write Sq.
    for (int t = T_; t < NST_; ++t) {
        _Float16* Sp = S[1 + ((t - T_) & 1)];
        _Float16* Sq = S[1 + (((t - T_) & 1) ^ 1)];
        {
            StepArgs q = a;
            q.nL2 = 0; q.nL1 = 512; q.nProj = 32; q.nCopy = 0;
            q.l1W = W1c2; q.l1Iters = 16; q.l1Ksh = 32; q.l1b = bc1;
            q.l1Alo = Sp; q.l1Ahi = Sp + 1152; q.l1H = Sq;
            q.pA = Sp + 1152; q.pOut = out + (size_t)(t - 1) * I_;
            fused_step<<<544, 256, 0, stream>>>(q);
        }
        {
            StepArgs q = a;
            q.nL2 = 512; q.nL1 = 0; q.nProj = 0; q.nCopy = 0;
            q.l2Alo = Sq; q.l2Ahi = Sp + 1152; q.l2H = Sq + 1152;
            fused_step<<<512, 256, 0, stream>>>(q);
        }
    }

    // final: proj(79) from h2(79)
    {
        _Float16* Sl = S[1 + (((NST_ - 1 - T_) & 1) ^ 1)];
        StepArgs q = a;
        q.nL2 = 0; q.nL1 = 0; q.nProj = 32; q.nCopy = 0;
        q.pA = Sl + 1152; q.pOut = out + (size_t)(NST_ - 1) * I_;
        fused_step<<<32, 256, 0, stream>>>(q);
    }
}